// Round 8
// baseline (135.691 us; speedup 1.0000x reference)
//
#include <hip/hip_runtime.h>
#include <hip/hip_bf16.h>

#define BD 8192
#define DD 1024
#define BM 128
#define BN 128
#define BKK 64
#define KSPLIT 4
#define NBLK (64 * 8 * KSPLIT)   // btiles * itiles * ksplit = 2048

typedef __attribute__((ext_vector_type(8))) short short8;
typedef __attribute__((ext_vector_type(4))) float floatx4;

__device__ inline float bf2f(unsigned short u) {
    union { unsigned int u; float f; } un;
    un.u = ((unsigned int)u) << 16;
    return un.f;
}
__device__ inline unsigned short f2bf(float f) {
    union { float f; unsigned int u; } un;
    un.f = f;
    unsigned int u = un.u;
    u += 0x7FFF + ((u >> 16) & 1);   // round-to-nearest-even
    return (unsigned short)(u >> 16);
}

__device__ inline void gld_lds16(const void* g, void* l) {
    __builtin_amdgcn_global_load_lds(
        (const __attribute__((address_space(1))) unsigned int*)g,
        (__attribute__((address_space(3))) unsigned int*)l, 16, 0, 0);
}

// Normalize: 4 rows per wave, 16 float4 loads issued up-front (latency hiding),
// 4 interleaved shuffle-reduce chains. Blocks 0..511 rna, 512..1023 atac,
// 1024..1087 link. 16 rows/block.
__global__ __launch_bounds__(256) void norm_all(const float* __restrict__ rna,
                                                const float* __restrict__ atac,
                                                const float* __restrict__ link,
                                                unsigned short* __restrict__ rnb,
                                                unsigned short* __restrict__ anb,
                                                unsigned short* __restrict__ linkb,
                                                float* __restrict__ er,
                                                float* __restrict__ ea) {
    int bid = blockIdx.x;
    int wid = threadIdx.x >> 6, lane = threadIdx.x & 63;
    const float* x;
    unsigned short* xb;
    float* ep;
    int rbase;
    bool ent = true;
    if (bid < 512)       { x = rna;  xb = rnb;   ep = er + bid;         rbase = bid * 16; }
    else if (bid < 1024) { x = atac; xb = anb;   ep = ea + (bid - 512); rbase = (bid - 512) * 16; }
    else                 { x = link; xb = linkb; ep = nullptr;          rbase = (bid - 1024) * 16; ent = false; }
    int r0 = rbase + wid * 4;   // 4 consecutive rows for this wave

    // Issue all 16 loads (4 rows x 4 float4) before any reduction.
    float4 v[4][4];
#pragma unroll
    for (int rr = 0; rr < 4; ++rr) {
        const float4* xr = (const float4*)(x + (size_t)(r0 + rr) * DD);
#pragma unroll
        for (int c = 0; c < 4; ++c) v[rr][c] = xr[lane + 64 * c];
    }

    // 4 interleaved sum-of-squares + shuffle-reduce chains.
    float ss[4];
#pragma unroll
    for (int rr = 0; rr < 4; ++rr) {
        ss[rr] = 0.f;
#pragma unroll
        for (int c = 0; c < 4; ++c)
            ss[rr] += v[rr][c].x * v[rr][c].x + v[rr][c].y * v[rr][c].y
                    + v[rr][c].z * v[rr][c].z + v[rr][c].w * v[rr][c].w;
    }
#pragma unroll
    for (int off = 1; off < 64; off <<= 1) {
#pragma unroll
        for (int rr = 0; rr < 4; ++rr) ss[rr] += __shfl_xor(ss[rr], off);
    }

    float epart = 0.f;
#pragma unroll
    for (int rr = 0; rr < 4; ++rr) {
        float inv = 1.0f / fmaxf(sqrtf(ss[rr]), 1e-12f);
        ushort4* orow = (ushort4*)(xb + (size_t)(r0 + rr) * DD);
#pragma unroll
        for (int c = 0; c < 4; ++c) {
            float a = v[rr][c].x * inv, b = v[rr][c].y * inv,
                  cc = v[rr][c].z * inv, d = v[rr][c].w * inv;
            ushort4 o;
            o.x = f2bf(a); o.y = f2bf(b); o.z = f2bf(cc); o.w = f2bf(d);
            orow[lane + 64 * c] = o;
            if (ent) {
                epart += a * __logf(a + 1e-8f) + b * __logf(b + 1e-8f)
                       + cc * __logf(cc + 1e-8f) + d * __logf(d + 1e-8f);
            }
        }
    }

    if (ent) {
#pragma unroll
        for (int off = 1; off < 64; off <<= 1) epart += __shfl_xor(epart, off);
        __shared__ float sw[4];
        if (lane == 0) sw[wid] = epart;
        __syncthreads();
        if (threadIdx.x == 0) ep[0] = sw[0] + sw[1] + sw[2] + sw[3];
    }
}

// Split-K GEMM (K/4 per block), sum-only fused epilogue -> one f32 per block.
// LDS exactly 32KB (As reused for the epilogue reduction) -> 5 blocks/CU resident.
__global__ __launch_bounds__(256) void gemm_cos(const unsigned short* __restrict__ anb,
                                                const unsigned short* __restrict__ linkb,
                                                const unsigned short* __restrict__ rnb,
                                                float* __restrict__ gpart) {
    __shared__ unsigned short As[BM * BKK];
    __shared__ unsigned short Bs[BN * BKK];

    // 2048 blocks = 64 btiles x 8 itiles x 4 ksplits; bid&7 = XCD.
    int bid = blockIdx.x;
    int j = bid >> 3;                      // 0..255
    int btile = (bid & 7) * 8 + (j & 7);   // 0..63
    int itile = (j >> 3) & 7;              // 0..7
    int ks = j >> 6;                       // 0..3
    int b0 = btile * BM;
    int i0 = itile * BN;
    int kbase = ks * (DD / KSPLIT);        // 256

    int tid = threadIdx.x;
    int wid = tid >> 6, lane = tid & 63;
    int wm = wid >> 1, wn = wid & 1;
    int r = lane & 15, kg = lane >> 4;

    // Staging: LDS linear dest; global source column pre-swizzled (rule 21).
    int srow = tid >> 3;
    int scb = (tid & 7) * 16;
    int scb_src = scb ^ ((srow & 7) << 4);

    const char* agbase = (const char*)anb + ((size_t)(b0 + srow) * DD + kbase) * 2 + scb_src;
    const char* bgbase = (const char*)linkb + ((size_t)(i0 + srow) * DD + kbase) * 2 + scb_src;
    unsigned short* al = As + srow * BKK + scb / 2;
    unsigned short* bl = Bs + srow * BKK + scb / 2;

    floatx4 acc[4][4];
#pragma unroll
    for (int m = 0; m < 4; ++m)
#pragma unroll
        for (int n = 0; n < 4; ++n) acc[m][n] = (floatx4)0.0f;

#pragma unroll
    for (int c = 0; c < 4; ++c) {
        gld_lds16(agbase + (size_t)c * 32 * DD * 2, al + c * 2048);
        gld_lds16(bgbase + (size_t)c * 32 * DD * 2, bl + c * 2048);
    }

    for (int step = 0; step < DD / KSPLIT / BKK; ++step) {   // 4 steps
        __syncthreads();
#pragma unroll
        for (int kk = 0; kk < 2; ++kk) {
            short8 a_[4], b_[4];
#pragma unroll
            for (int m = 0; m < 4; ++m) {
                int row = wm * 64 + m * 16 + r;
                int cb = (kg * 16 + kk * 64) ^ ((row & 7) << 4);
                a_[m] = *(const short8*)((const char*)As + row * 128 + cb);
            }
#pragma unroll
            for (int n = 0; n < 4; ++n) {
                int row = wn * 64 + n * 16 + r;
                int cb = (kg * 16 + kk * 64) ^ ((row & 7) << 4);
                b_[n] = *(const short8*)((const char*)Bs + row * 128 + cb);
            }
#pragma unroll
            for (int m = 0; m < 4; ++m)
#pragma unroll
                for (int n = 0; n < 4; ++n)
                    acc[m][n] = __builtin_amdgcn_mfma_f32_16x16x32_bf16(a_[m], b_[n], acc[m][n], 0, 0, 0);
        }
        __syncthreads();
        if (step < DD / KSPLIT / BKK - 1) {
            size_t kb = (size_t)(step + 1) * BKK * 2;
#pragma unroll
            for (int c = 0; c < 4; ++c) {
                gld_lds16(agbase + (size_t)c * 32 * DD * 2 + kb, al + c * 2048);
                gld_lds16(bgbase + (size_t)c * 32 * DD * 2 + kb, bl + c * 2048);
            }
        }
    }

    int b0w = b0 + wm * 64, i0w = i0 + wn * 64;
    float s = 0.f;
#pragma unroll
    for (int m = 0; m < 4; ++m) {
#pragma unroll
        for (int rr = 0; rr < 4; ++rr) {
            const unsigned short* rrow = rnb + (size_t)(b0w + m * 16 + kg * 4 + rr) * DD + i0w + r;
#pragma unroll
            for (int n = 0; n < 4; ++n)
                s += acc[m][n][rr] * bf2f(rrow[n * 16]);
        }
    }
#pragma unroll
    for (int off = 1; off < 64; off <<= 1) s += __shfl_xor(s, off);
    __syncthreads();                    // all waves done with As
    float* swb = (float*)As;            // reuse LDS, keep block at exactly 32KB
    if (lane == 0) swb[wid] = s;
    __syncthreads();
    if (tid == 0) gpart[bid] = swb[0] + swb[1] + swb[2] + swb[3];
}

__global__ __launch_bounds__(256) void finalize(const float* __restrict__ gpart,
                                                const float* __restrict__ er,
                                                const float* __restrict__ ea,
                                                const float* __restrict__ temp,
                                                float* __restrict__ out) {
    __shared__ float sb[4][3];
    float s = 0.f, se = 0.f, sa = 0.f;
    for (int i = threadIdx.x; i < NBLK; i += 256) s += gpart[i];
    for (int i = threadIdx.x; i < 512; i += 256) { se += er[i]; sa += ea[i]; }
#pragma unroll
    for (int off = 1; off < 64; off <<= 1) {
        s += __shfl_xor(s, off);
        se += __shfl_xor(se, off);
        sa += __shfl_xor(sa, off);
    }
    int wid = threadIdx.x >> 6, lane = threadIdx.x & 63;
    if (lane == 0) { sb[wid][0] = s; sb[wid][1] = se; sb[wid][2] = sa; }
    __syncthreads();
    if (threadIdx.x == 0) {
        float total = sb[0][0] + sb[1][0] + sb[2][0] + sb[3][0];
        float ser = sb[0][1] + sb[1][1] + sb[2][1] + sb[3][1];
        float sea = sb[0][2] + sb[1][2] + sb[2][2] + sb[3][2];
        float ent_rna = -ser / (float)BD;
        float ent_atac = -sea / (float)BD;
        float avg = 0.5f * (ent_rna + ent_atac);
        float t = temp[0];
        float sg = 1.0f / (1.0f + __expf(-t));
        float scale = sg * 0.1f + (1.0f - sg) * avg;
        float tau = fminf(fmaxf(scale, 0.01f), 1.0f);
        out[0] = -(total / (float)BD) / tau;
    }
}

extern "C" void kernel_launch(void* const* d_in, const int* in_sizes, int n_in,
                              void* d_out, int out_size, void* d_ws, size_t ws_size,
                              hipStream_t stream) {
    const float* z_rna = (const float*)d_in[0];
    const float* z_atac = (const float*)d_in[1];
    const float* link = (const float*)d_in[2];
    const float* temp = (const float*)d_in[3];
    float* out = (float*)d_out;

    char* ws = (char*)d_ws;
    float* gpart = (float*)ws;                          // 2048 f32 = 8KB
    float* er_part = (float*)(ws + 8192);               // 512 f32
    float* ea_part = (float*)(ws + 16384);              // 512 f32
    unsigned short* linkb = (unsigned short*)(ws + 32768);                       // 2 MB
    unsigned short* rnb = (unsigned short*)(ws + 32768 + 2097152);               // 16 MB
    unsigned short* anb = (unsigned short*)(ws + 32768 + 2097152 + 16777216);    // 16 MB

    // No memset needed: every partial slot is written unconditionally.
    norm_all<<<1088, 256, 0, stream>>>(z_rna, z_atac, link, rnb, anb, linkb, er_part, ea_part);
    gemm_cos<<<NBLK, 256, 0, stream>>>(anb, linkb, rnb, gpart);
    finalize<<<1, 256, 0, stream>>>(gpart, er_part, ea_part, temp, out);
}